// Round 1
// baseline (300.776 us; speedup 1.0000x reference)
//
#include <hip/hip_runtime.h>
#include <math.h>

// Problem constants (match reference)
#define BB 64
#define NN 4096
#define DD 256
#define EPS 1e-8f
#define INV_TEMP 10.0f   // 1 / TEMPERATURE

// One block (= one wave of 64 lanes) per sample b.
// Each lane loads float4 slices of anchor / positive / negative (64*4 = 256 = D),
// accumulates 5 partial dot products, wave-reduces, lane 0 computes the loss
// term and atomically accumulates loss/B into out[0].
__global__ __launch_bounds__(64) void gcl_kernel(
    const float* __restrict__ emb,
    const int* __restrict__ anchor_idx,
    const int* __restrict__ pos_idx,
    const int* __restrict__ neg_graph_idx,
    const int* __restrict__ neg_node_idx,
    float* __restrict__ out)
{
    const int b = blockIdx.x;
    const int t = threadIdx.x;  // 0..63

    const int ai  = anchor_idx[b];
    const int pi  = pos_idx[b];
    const int ngi = neg_graph_idx[b];
    const int nni = neg_node_idx[b];

    const float4* __restrict__ a = (const float4*)(emb + ((size_t)b   * NN + ai)  * DD);
    const float4* __restrict__ p = (const float4*)(emb + ((size_t)b   * NN + pi)  * DD);
    const float4* __restrict__ n = (const float4*)(emb + ((size_t)ngi * NN + nni) * DD);

    const float4 av = a[t];
    const float4 pv = p[t];
    const float4 nv = n[t];

    float dap = av.x*pv.x + av.y*pv.y + av.z*pv.z + av.w*pv.w;
    float daa = av.x*av.x + av.y*av.y + av.z*av.z + av.w*av.w;
    float dpp = pv.x*pv.x + pv.y*pv.y + pv.z*pv.z + pv.w*pv.w;
    float dan = av.x*nv.x + av.y*nv.y + av.z*nv.z + av.w*nv.w;
    float dnn = nv.x*nv.x + nv.y*nv.y + nv.z*nv.z + nv.w*nv.w;

    // Wave-64 butterfly reduction (wavefront = 64 on CDNA)
    #pragma unroll
    for (int off = 32; off > 0; off >>= 1) {
        dap += __shfl_down(dap, off);
        daa += __shfl_down(daa, off);
        dpp += __shfl_down(dpp, off);
        dan += __shfl_down(dan, off);
        dnn += __shfl_down(dnn, off);
    }

    if (t == 0) {
        const float na  = fmaxf(sqrtf(daa), EPS);
        const float npn = fmaxf(sqrtf(dpp), EPS);
        const float nnn = fmaxf(sqrtf(dnn), EPS);
        const float pos_sim = dap / (na * npn) * INV_TEMP;
        const float neg_sim = dan / (na * nnn) * INV_TEMP;
        const float x = neg_sim - pos_sim;
        // logaddexp(0, x) = max(x,0) + log1p(exp(-|x|))  (numerically stable)
        const float loss = fmaxf(x, 0.0f) + log1pf(expf(-fabsf(x)));
        atomicAdd(out, loss * (1.0f / BB));
    }
}

extern "C" void kernel_launch(void* const* d_in, const int* in_sizes, int n_in,
                              void* d_out, int out_size, void* d_ws, size_t ws_size,
                              hipStream_t stream) {
    const float* emb           = (const float*)d_in[0];
    // d_in[1] = graph_labels (unused by the reference computation)
    const int* anchor_idx      = (const int*)d_in[2];
    const int* pos_idx         = (const int*)d_in[3];
    const int* neg_graph_idx   = (const int*)d_in[4];
    const int* neg_node_idx    = (const int*)d_in[5];
    float* out                 = (float*)d_out;

    // d_out is poisoned with 0xAA before each timed launch — zero it first.
    hipMemsetAsync(out, 0, sizeof(float), stream);
    gcl_kernel<<<BB, 64, 0, stream>>>(emb, anchor_idx, pos_idx,
                                      neg_graph_idx, neg_node_idx, out);
}